// Round 8
// baseline (1390.567 us; speedup 1.0000x reference)
//
#include <hip/hip_runtime.h>

#define T_STEPS 512
#define NTRAJ   4096
#define LAT     32
#define INPD    16
#define HID     20
#define CAT     48

__device__ __forceinline__ float fast_tanh(float x) {
    float e = __expf(2.0f * x);
    float r = __builtin_amdgcn_rcpf(e + 1.0f);
    return fmaf(-2.0f, r, 1.0f);
}
__device__ __forceinline__ float fast_sigmoid(float x) {
    float e = __expf(-x);
    return __builtin_amdgcn_rcpf(e + 1.0f);
}

// Read v rotated right by I within each 16-lane row (DPP row_ror:I).
// Lane l reads lane (l & ~15) | ((l - I) & 15). Same semantics as the
// R3/R4-verified tables. mov_dpp (no old operand) is the fold-friendly form.
template<int I> __device__ __forceinline__ float ror16(float v) {
    if constexpr (I == 0) {
        return v;
    } else {
        return __int_as_float(__builtin_amdgcn_mov_dpp(
            __float_as_int(v), 0x120 | I, 0xF, 0xF, false));
    }
}

// Ring-MAC macros. ACC is a float[4]; i is a literal rotation index.
#define MPA(i, ACC, Y, Y2, X) \
    ACC[(i)&3]     = fmaf(ror16<(i)>(Y),  wa_a[(i)], ACC[(i)&3]); \
    ACC[((i)+1)&3] = fmaf(ror16<(i)>(Y2), wa_b[(i)], ACC[((i)+1)&3]); \
    ACC[((i)+2)&3] = fmaf(ror16<(i)>(X),  wa_x[(i)], ACC[((i)+2)&3]);
#define MPB(i, ACC, H, H2, X) \
    ACC[(i)&3]     = fmaf(ror16<(i)>(H),  wb_a[(i)], ACC[(i)&3]); \
    ACC[((i)+1)&3] = fmaf(ror16<(i)>(H2), wb_b[(i)], ACC[((i)+1)&3]);
#define MPC(i, ACC, RY, RY2, X) \
    ACC[(i)&3]     = fmaf(ror16<(i)>(RY),  wc_a[(i)], ACC[(i)&3]); \
    ACC[((i)+1)&3] = fmaf(ror16<(i)>(RY2), wc_b[(i)], ACC[((i)+1)&3]); \
    ACC[((i)+2)&3] = fmaf(ror16<(i)>(X),   wc_x[(i)], ACC[((i)+2)&3]);
#define MPD(i, ACC, HN, HN2, X) \
    ACC[(i)&3]     = fmaf(ror16<(i)>(HN),  wd_a[(i)], ACC[(i)&3]); \
    ACC[((i)+1)&3] = fmaf(ror16<(i)>(HN2), wd_b[(i)], ACC[((i)+1)&3]);

#define REP16(M, ACC, S1, S2, S3) \
    M(0,ACC,S1,S2,S3)  M(1,ACC,S1,S2,S3)  M(2,ACC,S1,S2,S3)  M(3,ACC,S1,S2,S3) \
    M(4,ACC,S1,S2,S3)  M(5,ACC,S1,S2,S3)  M(6,ACC,S1,S2,S3)  M(7,ACC,S1,S2,S3) \
    M(8,ACC,S1,S2,S3)  M(9,ACC,S1,S2,S3)  M(10,ACC,S1,S2,S3) M(11,ACC,S1,S2,S3) \
    M(12,ACC,S1,S2,S3) M(13,ACC,S1,S2,S3) M(14,ACC,S1,S2,S3) M(15,ACC,S1,S2,S3)

#define RED4(A) ((A[0] + A[1]) + (A[2] + A[3]))

// One wave = TWO trajectories (A,B) interleaved at phase granularity, sharing
// one 160-entry register weight file. Pure intrinsics (no inline asm) — the
// allocator variant that measured copy-free (R3). Lane layout: c = lane&31
// (column), g = lane>>5 (u/r gate), p = (lane>>4)&1 (row parity).
__global__ __launch_bounds__(64, 1) void rnn_fused(
    const float* __restrict__ data,
    const float* __restrict__ Wu1, const float* __restrict__ bu1,
    const float* __restrict__ Wu2, const float* __restrict__ bu2,
    const float* __restrict__ Wr1, const float* __restrict__ br1,
    const float* __restrict__ Wr2, const float* __restrict__ br2,
    const float* __restrict__ Wn1, const float* __restrict__ bn1,
    const float* __restrict__ Wn2, const float* __restrict__ bn2,
    float* __restrict__ out_yi, float* __restrict__ out_lat)
{
    const int lane = threadIdx.x & 63;
    const int c    = lane & 31;
    const int g    = lane >> 5;
    const int p    = (lane >> 4) & 1;
    const int bA   = blockIdx.x * 2;
    const int bB   = bA + 1;

    const float* W1 = g ? Wr1 : Wu1;
    const float* B1 = g ? br1 : bu1;
    const float* W2 = g ? Wr2 : Wu2;
    const float* B2 = g ? br2 : bu2;
    const bool realc = (c < HID);

    // Stationary per-lane weights, indexed by rotation step i (R3-verified).
    //   nat ring  -> slot sa = 16*p     + ((c-i)&15)
    //   swap ring -> slot sb = 16*(1-p) + ((c-i)&15)
    //   x ring    -> slot sx = 32       + ((c-i)&15)
    float wa_a[16], wa_b[16], wa_x[16], wb_a[16], wb_b[16];
    float wc_a[16], wc_b[16], wc_x[16], wd_a[16], wd_b[16];
    #pragma unroll
    for (int i = 0; i < 16; ++i) {
        int s  = (c - i) & 15;
        int sa = 16 * p + s;
        int sb = 16 * (1 - p) + s;
        int sx = 32 + s;
        wa_a[i] = realc ? W1[sa * HID + c] : 0.0f;
        wa_b[i] = realc ? W1[sb * HID + c] : 0.0f;
        wa_x[i] = realc ? W1[sx * HID + c] : 0.0f;
        wb_a[i] = (sa < HID) ? W2[sa * LAT + c] : 0.0f;
        wb_b[i] = (sb < HID) ? W2[sb * LAT + c] : 0.0f;
        wc_a[i] = realc ? Wn1[sa * HID + c] : 0.0f;
        wc_b[i] = realc ? Wn1[sb * HID + c] : 0.0f;
        wc_x[i] = realc ? Wn1[sx * HID + c] : 0.0f;
        wd_a[i] = (sa < HID) ? Wn2[sa * LAT + c] : 0.0f;
        wd_b[i] = (sb < HID) ? Wn2[sb * LAT + c] : 0.0f;
    }
    const float ba = realc ? B1[c] : 0.0f;
    const float bb = B2[c];
    const float bc = realc ? bn1[c] : 0.0f;
    const float bd = bn2[c];

    // x rings: lane l holds x[l&15]; 2-step prefetch pipeline per trajectory.
    const float* xpA = data + (size_t)bA * T_STEPS * INPD + (lane & 15);
    const float* xpB = data + (size_t)bB * T_STEPS * INPD + (lane & 15);
    float x0A = xpA[0],    x0B = xpB[0];
    float x1A = xpA[INPD], x1B = xpB[INPD];

    float yA = 0.0f, y2A = 0.0f;   // y[c], y[c^16] on all lanes
    float yB = 0.0f, y2B = 0.0f;
    float* olA = out_lat + (size_t)bA * T_STEPS * LAT + c;
    float* olB = out_lat + (size_t)bB * T_STEPS * LAT + c;

    for (int t = 0; t < T_STEPS; ++t) {
        int tf = t + 2; tf = (tf < T_STEPS) ? tf : (T_STEPS - 1);
        float xnA = xpA[(size_t)tf * INPD];
        float xnB = xpB[(size_t)tf * INPD];

        // ---- Phase A: layer-1 of own gate, K=48 = y(32) + x(16) ----
        float aA[4] = {ba, 0.f, 0.f, 0.f};
        float aB[4] = {ba, 0.f, 0.f, 0.f};
        REP16(MPA, aA, yA, y2A, x0A)
        REP16(MPA, aB, yB, y2B, x0B)
        float h1A = fast_tanh(RED4(aA));
        float h1B = fast_tanh(RED4(aB));
        float h2A = __shfl_xor(h1A, 16);
        float h2B = __shfl_xor(h1B, 16);

        // ---- Phase B: layer-2 of own gate, K=20 (ring-padded to 32) ----
        float bqA[4] = {bb, 0.f, 0.f, 0.f};
        float bqB[4] = {bb, 0.f, 0.f, 0.f};
        REP16(MPB, bqA, h1A, h2A, 0)
        REP16(MPB, bqB, h1B, h2B, 0)
        float gateA = fast_sigmoid(RED4(bqA));
        float gateB = fast_sigmoid(RED4(bqB));

        float exchA = __shfl_xor(gateA, 32);
        float exchB = __shfl_xor(gateB, 32);
        float uA = g ? exchA : gateA;
        float uB = g ? exchB : gateB;
        float rA = g ? gateA : exchA;
        float rB = g ? gateB : exchB;
        float ryA = rA * yA;
        float ryB = rB * yB;
        float ry2A = __shfl_xor(ryA, 16);
        float ry2B = __shfl_xor(ryB, 16);

        // ---- Phase C: layer-1 of n, K=48 = ry(32) + x(16) ----
        float cqA[4] = {bc, 0.f, 0.f, 0.f};
        float cqB[4] = {bc, 0.f, 0.f, 0.f};
        REP16(MPC, cqA, ryA, ry2A, x0A)
        REP16(MPC, cqB, ryB, ry2B, x0B)
        float hnA = fast_tanh(RED4(cqA));
        float hnB = fast_tanh(RED4(cqB));
        float hn2A = __shfl_xor(hnA, 16);
        float hn2B = __shfl_xor(hnB, 16);

        // ---- Phase D: layer-2 of n, K=20 (ring-padded to 32) ----
        float dqA[4] = {bd, 0.f, 0.f, 0.f};
        float dqB[4] = {bd, 0.f, 0.f, 0.f};
        REP16(MPD, dqA, hnA, hn2A, 0)
        REP16(MPD, dqB, hnB, hn2B, 0)
        float nA = fast_tanh(RED4(dqA));
        float nB = fast_tanh(RED4(dqB));

        // ---- y' = (1-u)*n + u*y ----
        float nyA = fmaf(uA, yA - nA, nA);
        float nyB = fmaf(uB, yB - nB, nB);
        yA = nyA; yB = nyB;
        y2A = __shfl_xor(nyA, 16);
        y2B = __shfl_xor(nyB, 16);
        if (lane < 32) {
            olA[(size_t)t * LAT] = nyA;
            olB[(size_t)t * LAT] = nyB;
        }

        x0A = x1A; x1A = xnA;
        x0B = x1B; x1B = xnB;
    }

    if (lane < 32) {
        out_yi[(size_t)bA * LAT + c] = yA;
        out_yi[(size_t)bB * LAT + c] = yB;
    }
}

extern "C" void kernel_launch(void* const* d_in, const int* in_sizes, int n_in,
                              void* d_out, int out_size, void* d_ws, size_t ws_size,
                              hipStream_t stream) {
    const float* data = (const float*)d_in[0];
    const float* Wu1 = (const float*)d_in[2];
    const float* bu1 = (const float*)d_in[3];
    const float* Wu2 = (const float*)d_in[4];
    const float* bu2 = (const float*)d_in[5];
    const float* Wr1 = (const float*)d_in[6];
    const float* br1 = (const float*)d_in[7];
    const float* Wr2 = (const float*)d_in[8];
    const float* br2 = (const float*)d_in[9];
    const float* Wn1 = (const float*)d_in[10];
    const float* bn1 = (const float*)d_in[11];
    const float* Wn2 = (const float*)d_in[12];
    const float* bn2 = (const float*)d_in[13];

    float* out_yi  = (float*)d_out;
    float* out_lat = out_yi + (size_t)NTRAJ * LAT;

    rnn_fused<<<NTRAJ / 2, 64, 0, stream>>>(
        data, Wu1, bu1, Wu2, bu2, Wr1, br1, Wr2, br2, Wn1, bn1, Wn2, bn2,
        out_yi, out_lat);
}